// Round 3
// baseline (5175.457 us; speedup 1.0000x reference)
//
#include <hip/hip_runtime.h>
#include <math.h>

#define NEGV (-1e9f)

// ---------------- Threefry-2x32 (exact JAX semantics) ----------------
__host__ __device__ inline unsigned rotl32(unsigned v, int d){ return (v<<d)|(v>>(32-d)); }

__host__ __device__ inline void tf2x32(unsigned k0, unsigned k1, unsigned c0, unsigned c1,
                                       unsigned* o0, unsigned* o1){
  unsigned ks2 = k0 ^ k1 ^ 0x1BD11BDAu;
  unsigned x0 = c0 + k0, x1 = c1 + k1;
#define RND(r) { x0 += x1; x1 = rotl32(x1,(r)); x1 ^= x0; }
  RND(13) RND(15) RND(26) RND(6)   x0 += k1;  x1 += ks2 + 1u;
  RND(17) RND(29) RND(16) RND(24)  x0 += ks2; x1 += k0  + 2u;
  RND(13) RND(15) RND(26) RND(6)   x0 += k0;  x1 += k1  + 3u;
  RND(17) RND(29) RND(16) RND(24)  x0 += k1;  x1 += ks2 + 4u;
  RND(13) RND(15) RND(26) RND(6)   x0 += ks2; x1 += k0  + 5u;
#undef RND
  *o0 = x0; *o1 = x1;
}

// ---------------- embedding: x = word_emb[seq] + pos_emb[pos] ----------------
__global__ void emb_kernel(const int* __restrict__ seq, const int* __restrict__ pos,
                           const float* __restrict__ we, const float* __restrict__ pe,
                           float* __restrict__ x){
  int t = blockIdx.x; int tid = threadIdx.x;  // 128 threads, float4 each
  int id = seq[t]; int pp = pos[t];
  float4 w = ((const float4*)(we + (size_t)id*512))[tid];
  float4 p = ((const float4*)(pe + (size_t)pp*512))[tid];
  float4 o; o.x=w.x+p.x; o.y=w.y+p.y; o.z=w.z+p.z; o.w=w.w+p.w;
  ((float4*)(x + (size_t)t*512))[tid] = o;
}

// ---------------- probs -> bernoulli -> keep flags ----------------
__global__ __launch_bounds__(64) void probs_keep_kernel(const float* __restrict__ x,
        const float* __restrict__ sw, const float* __restrict__ sb,
        unsigned k0, unsigned k1, int* __restrict__ keep){
  int t = blockIdx.x; int lane = threadIdx.x;
  const float* row = x + (size_t)t*512;
  float acc = 0.f;
  #pragma unroll
  for (int i=0;i<8;i++){ int d = lane + (i<<6); acc += row[d]*sw[d]; }
  #pragma unroll
  for (int o=32;o;o>>=1) acc += __shfl_xor(acc, o);
  if (lane==0){
    float z = acc + sb[0];
    float p = 1.f/(1.f + expf(-z));
    unsigned y0,y1; tf2x32(k0,k1, 0u,(unsigned)t, &y0,&y1);
    unsigned bits = y0 ^ y1;                       // partitionable 32-bit path
    float u = __uint_as_float((bits>>9) | 0x3f800000u) - 1.0f;
    keep[t] = (u < p) ? 0 : 1;                     // keep = !drop
  }
}

// ---------------- per-row stable compaction map ----------------
__global__ void scan_kernel(const int* __restrict__ keep, int* __restrict__ map,
                            int* __restrict__ nkeep){
  int b = blockIdx.x; int s = threadIdx.x;   // 512 threads
  __shared__ int sc[512];
  int k = keep[(b<<9) + s];
  sc[s] = k;
  __syncthreads();
  for (int o=1;o<512;o<<=1){
    int t = (s>=o) ? sc[s-o] : 0;
    __syncthreads();
    sc[s] += t;
    __syncthreads();
  }
  if (k) map[(b<<9) + sc[s] - 1] = s;
  if (s==511) nkeep[b] = sc[511];
}

__global__ void gather_kernel(const float* __restrict__ src, float* __restrict__ dst,
                              const int* __restrict__ map, const int* __restrict__ nkeep){
  int blk = blockIdx.x; int b = blk >> 9; int j = blk & 511; int tid = threadIdx.x; // 128
  float4* drow = (float4*)(dst + (size_t)blk*512);
  if (j < nkeep[b]){
    const float4* srow = (const float4*)(src + (size_t)((b<<9) + map[blk])*512);
    drow[tid] = srow[tid];
  } else {
    drow[tid] = make_float4(0.f,0.f,0.f,0.f);
  }
}

// ---------------- Wq/Wk/Wv [H,D,DK] -> row-major [D, H*DK] ----------------
__global__ void wqkv_kernel(const float* __restrict__ Wq, const float* __restrict__ Wk,
                            const float* __restrict__ Wv, float* __restrict__ Wt){
  int d = blockIdx.x; int which = blockIdx.y; int c = threadIdx.x;  // 512 threads
  const float* src = (which==0)? Wq : (which==1)? Wk : Wv;
  Wt[((size_t)which<<18) + ((size_t)d<<9) + c] =
      src[(size_t)(c>>6)*32768 + ((size_t)d<<6) + (c&63)];
}

// ---------------- fp32 tiled GEMM 64x64x16, C = A@B (+bias)(+R)(relu) ----------------
template<bool BIAS, bool RES, bool RELU>
__global__ __launch_bounds__(256) void gemm_kernel(const float* __restrict__ A,
        const float* __restrict__ Bm, const float* __restrict__ bias,
        const float* __restrict__ R, float* __restrict__ C, int M, int N, int K){
  __shared__ float As[16][64];   // [k][m]
  __shared__ float Bs[16][64];   // [k][n]
  int bn = blockIdx.x, bm = blockIdx.y;
  int tid = threadIdx.x;
  int tx = tid & 15, ty = tid >> 4;
  int arow = tid >> 2,  acg = (tid & 3) << 2;
  int brow = tid >> 4,  bcg = (tid & 15) << 2;
  const float* Ab = A + (size_t)bm*64*K;
  const float* Bb = Bm + (bn<<6);
  float acc[4][4] = {};
  for (int k0 = 0; k0 < K; k0 += 16){
    float4 av = *(const float4*)(Ab + (size_t)arow*K + k0 + acg);
    float4 bv = *(const float4*)(Bb + (size_t)(k0+brow)*N + bcg);
    __syncthreads();
    As[acg+0][arow]=av.x; As[acg+1][arow]=av.y; As[acg+2][arow]=av.z; As[acg+3][arow]=av.w;
    *(float4*)&Bs[brow][bcg] = bv;
    __syncthreads();
    #pragma unroll
    for (int kk=0;kk<16;kk++){
      float4 a = *(const float4*)&As[kk][ty<<2];
      float4 b = *(const float4*)&Bs[kk][tx<<2];
      acc[0][0] += a.x*b.x; acc[0][1] += a.x*b.y; acc[0][2] += a.x*b.z; acc[0][3] += a.x*b.w;
      acc[1][0] += a.y*b.x; acc[1][1] += a.y*b.y; acc[1][2] += a.y*b.z; acc[1][3] += a.y*b.w;
      acc[2][0] += a.z*b.x; acc[2][1] += a.z*b.y; acc[2][2] += a.z*b.z; acc[2][3] += a.z*b.w;
      acc[3][0] += a.w*b.x; acc[3][1] += a.w*b.y; acc[3][2] += a.w*b.z; acc[3][3] += a.w*b.w;
    }
  }
  int row0 = (bm<<6) + (ty<<2), col0 = (bn<<6) + (tx<<2);
  #pragma unroll
  for (int i=0;i<4;i++){
    #pragma unroll
    for (int j=0;j<4;j++){
      float v = acc[i][j];
      if (BIAS) v += bias[col0+j];
      if (RES)  v += R[(size_t)(row0+i)*N + col0+j];
      if (RELU) v = fmaxf(v, 0.f);
      C[(size_t)(row0+i)*N + col0+j] = v;
    }
  }
}

// ---------------- fused attention: 8 queries per 1-wave block ----------------
__global__ __launch_bounds__(64) void attn_kernel(const float* __restrict__ Q,
        const float* __restrict__ Kb, const float* __restrict__ Vb,
        const float* __restrict__ Xc, float* __restrict__ O){
  int blk = blockIdx.x;                 // (b*8 + h)*64 + qt
  int qt = blk & 63; int bh = blk >> 6; int h = bh & 7; int b = bh >> 3;
  int lane = threadIdx.x;
  __shared__ float qs[8][64];
  __shared__ float ps[8][512];
  __shared__ float pads[512];
  size_t base = ((size_t)b<<18) + ((size_t)h<<6);   // (b*512 + s)*512 + h*64
  int q0 = qt << 3;
  #pragma unroll
  for (int j=0;j<8;j++) qs[j][lane] = Q[base + (size_t)(q0+j)*512 + lane];
  #pragma unroll
  for (int i=0;i<8;i++){ int s = lane + (i<<6); pads[s] = Xc[(size_t)((b<<9)+s)*512]; }
  __syncthreads();
  const float scale = 22.62741699796952f;   // sqrt(512)
  for (int i=0;i<8;i++){
    int s = lane + (i<<6);
    const float* kr = Kb + base + (size_t)s*512;
    float a0=0,a1=0,a2=0,a3=0,a4=0,a5=0,a6=0,a7=0;
    for (int d=0; d<64; d++){
      float kv = kr[d];
      a0 += qs[0][d]*kv; a1 += qs[1][d]*kv; a2 += qs[2][d]*kv; a3 += qs[3][d]*kv;
      a4 += qs[4][d]*kv; a5 += qs[5][d]*kv; a6 += qs[6][d]*kv; a7 += qs[7][d]*kv;
    }
    bool pad = (pads[s] == 0.f);
    ps[0][s] = pad? NEGV : a0/scale;  ps[1][s] = pad? NEGV : a1/scale;
    ps[2][s] = pad? NEGV : a2/scale;  ps[3][s] = pad? NEGV : a3/scale;
    ps[4][s] = pad? NEGV : a4/scale;  ps[5][s] = pad? NEGV : a5/scale;
    ps[6][s] = pad? NEGV : a6/scale;  ps[7][s] = pad? NEGV : a7/scale;
  }
  __syncthreads();
  float denom[8];
  #pragma unroll
  for (int j=0;j<8;j++){
    float m = -3.0e38f;
    #pragma unroll
    for (int i=0;i<8;i++) m = fmaxf(m, ps[j][lane + (i<<6)]);
    #pragma unroll
    for (int o=32;o;o>>=1) m = fmaxf(m, __shfl_xor(m,o));
    float sm = 0.f;
    #pragma unroll
    for (int i=0;i<8;i++){
      int s = lane + (i<<6);
      float e = expf(ps[j][s] - m);
      ps[j][s] = e;
      sm += e;
    }
    #pragma unroll
    for (int o=32;o;o>>=1) sm += __shfl_xor(sm,o);
    denom[j] = sm;
  }
  __syncthreads();
  float outv[8] = {0,0,0,0,0,0,0,0};
  for (int s=0;s<512;s++){
    float vv = Vb[base + (size_t)s*512 + lane];
    #pragma unroll
    for (int j=0;j<8;j++) outv[j] += ps[j][s]*vv;
  }
  #pragma unroll
  for (int j=0;j<8;j++) O[base + (size_t)(q0+j)*512 + lane] = outv[j] / denom[j];
}

// ---------------- LayerNorm (torch-style: unbiased std, eps added to sd) ----------------
__global__ __launch_bounds__(256) void ln_kernel(const float* __restrict__ in,
        const float* __restrict__ ga, const float* __restrict__ be, float* __restrict__ out){
  int t = blockIdx.x; int tid = threadIdx.x;
  const float* row = in + (size_t)t*512;
  float v0 = row[tid], v1 = row[tid+256];
  float s = v0 + v1;
  #pragma unroll
  for (int o=32;o;o>>=1) s += __shfl_xor(s,o);
  __shared__ float red[4];
  int wid = tid >> 6, lane = tid & 63;
  if (lane==0) red[wid] = s;
  __syncthreads();
  float mu = (red[0]+red[1]+red[2]+red[3]) * (1.f/512.f);
  float d0 = v0-mu, d1 = v1-mu;
  float q = d0*d0 + d1*d1;
  #pragma unroll
  for (int o=32;o;o>>=1) q += __shfl_xor(q,o);
  __syncthreads();
  if (lane==0) red[wid] = q;
  __syncthreads();
  float var = (red[0]+red[1]+red[2]+red[3]) * (1.f/511.f);
  float inv = 1.f/(sqrtf(var) + 1e-3f);
  float* orow = out + (size_t)t*512;
  orow[tid]     = ga[tid]    *(d0*inv) + be[tid];
  orow[tid+256] = ga[tid+256]*(d1*inv) + be[tid+256];
}

// ---------------- launch ----------------
extern "C" void kernel_launch(void* const* d_in, const int* in_sizes, int n_in,
                              void* d_out, int out_size, void* d_ws, size_t ws_size,
                              hipStream_t stream){
  const int*   seq = (const int*)d_in[0];
  const int*   pos = (const int*)d_in[1];
  const float* we  = (const float*)d_in[2];
  const float* pe  = (const float*)d_in[3];
  const float* Wq  = (const float*)d_in[4];
  const float* Wk  = (const float*)d_in[5];
  const float* Wv  = (const float*)d_in[6];
  const float* Wo  = (const float*)d_in[7];
  const float* bo  = (const float*)d_in[8];
  const float* l1a = (const float*)d_in[9];
  const float* l1b = (const float*)d_in[10];
  const float* w1  = (const float*)d_in[11];
  const float* b1  = (const float*)d_in[12];
  const float* w2  = (const float*)d_in[13];
  const float* b2  = (const float*)d_in[14];
  const float* l2a = (const float*)d_in[15];
  const float* l2b = (const float*)d_in[16];
  const float* sw  = (const float*)d_in[17];
  const float* sb  = (const float*)d_in[18];
  float* out = (float*)d_out;

  const size_t TD = (size_t)8192*512;       // 4M floats per [B,S,D] slab
  float* A  = (float*)d_ws;                 // x (layer input / scratch)
  float* Bc = A  + TD;                      // compacted x (residual)
  float* Qb = Bc + TD;
  float* Kb = Qb + TD;
  float* Vb = Kb + TD;
  float* Hb = Kb;                           // FFN hidden aliases K|V (8192x1024)
  float* Wt = Vb + TD;                      // 3 x 512 x 512 transposed qkv weights
  int* keep = (int*)(Wt + 3*512*512);
  int* map  = keep + 8192;
  int* nk   = map  + 8192;

  // deterministic host-side key chain: rng=key(42); per layer rng,sub = split(rng)
  unsigned r0=0u, r1=42u, subs0[6], subs1[6];
  for (int l=0;l<6;l++){
    unsigned a0,a1,b0,b1;
    tf2x32(r0,r1, 0u,0u, &a0,&a1);   // new rng = fold(rng, 0)
    tf2x32(r0,r1, 0u,1u, &b0,&b1);   // sub     = fold(rng, 1)
    subs0[l]=b0; subs1[l]=b1; r0=a0; r1=a1;
  }

  emb_kernel<<<8192,128,0,stream>>>(seq,pos,we,pe,A);

  for (int l=0;l<6;l++){
    probs_keep_kernel<<<8192,64,0,stream>>>(A, sw + (size_t)l*512, sb + l,
                                            subs0[l], subs1[l], keep);
    scan_kernel<<<16,512,0,stream>>>(keep, map, nk);
    gather_kernel<<<8192,128,0,stream>>>(A, Bc, map, nk);
    wqkv_kernel<<<dim3(512,3),512,0,stream>>>(Wq + (size_t)l*262144,
                                              Wk + (size_t)l*262144,
                                              Wv + (size_t)l*262144, Wt);
    gemm_kernel<false,false,false><<<dim3(8,128),256,0,stream>>>(Bc, Wt,
            nullptr, nullptr, Qb, 8192,512,512);
    gemm_kernel<false,false,false><<<dim3(8,128),256,0,stream>>>(Bc, Wt+262144,
            nullptr, nullptr, Kb, 8192,512,512);
    gemm_kernel<false,false,false><<<dim3(8,128),256,0,stream>>>(Bc, Wt+524288,
            nullptr, nullptr, Vb, 8192,512,512);
    attn_kernel<<<8192,64,0,stream>>>(Qb, Kb, Vb, Bc, A);
    gemm_kernel<true,true,false><<<dim3(8,128),256,0,stream>>>(A, Wo + (size_t)l*262144,
            bo + (size_t)l*512, Bc, Qb, 8192,512,512);
    ln_kernel<<<8192,256,0,stream>>>(Qb, l1a + (size_t)l*512, l1b + (size_t)l*512, A);
    gemm_kernel<true,false,true><<<dim3(16,128),256,0,stream>>>(A, w1 + (size_t)l*524288,
            b1 + (size_t)l*1024, nullptr, Hb, 8192,1024,512);
    gemm_kernel<true,true,false><<<dim3(8,128),256,0,stream>>>(Hb, w2 + (size_t)l*524288,
            b2 + (size_t)l*512, A, Qb, 8192,512,1024);
    ln_kernel<<<8192,256,0,stream>>>(Qb, l2a + (size_t)l*512, l2b + (size_t)l*512,
                                     (l==5)? out : A);
  }
}

// Round 8
// 3720.314 us; speedup vs baseline: 1.3911x; 1.3911x over previous
//
#include <hip/hip_runtime.h>
#include <math.h>

#define NEGV (-1e9f)
#define ISCALE 0.04419417382415922f   // 1/sqrt(512)

// ---------------- Threefry-2x32 (exact JAX semantics) ----------------
__host__ __device__ inline unsigned rotl32(unsigned v, int d){ return (v<<d)|(v>>(32-d)); }

__host__ __device__ inline void tf2x32(unsigned k0, unsigned k1, unsigned c0, unsigned c1,
                                       unsigned* o0, unsigned* o1){
  unsigned ks2 = k0 ^ k1 ^ 0x1BD11BDAu;
  unsigned x0 = c0 + k0, x1 = c1 + k1;
#define RND(r) { x0 += x1; x1 = rotl32(x1,(r)); x1 ^= x0; }
  RND(13) RND(15) RND(26) RND(6)   x0 += k1;  x1 += ks2 + 1u;
  RND(17) RND(29) RND(16) RND(24)  x0 += ks2; x1 += k0  + 2u;
  RND(13) RND(15) RND(26) RND(6)   x0 += k0;  x1 += k1  + 3u;
  RND(17) RND(29) RND(16) RND(24)  x0 += k1;  x1 += ks2 + 4u;
  RND(13) RND(15) RND(26) RND(6)   x0 += ks2; x1 += k0  + 5u;
#undef RND
  *o0 = x0; *o1 = x1;
}

// ---------------- embedding ----------------
__global__ void emb_kernel(const int* __restrict__ seq, const int* __restrict__ pos,
                           const float* __restrict__ we, const float* __restrict__ pe,
                           float* __restrict__ x){
  int t = blockIdx.x; int tid = threadIdx.x;
  int id = seq[t]; int pp = pos[t];
  float4 w = ((const float4*)(we + (size_t)id*512))[tid];
  float4 p = ((const float4*)(pe + (size_t)pp*512))[tid];
  float4 o; o.x=w.x+p.x; o.y=w.y+p.y; o.z=w.z+p.z; o.w=w.w+p.w;
  ((float4*)(x + (size_t)t*512))[tid] = o;
}

// ---------------- probs -> bernoulli -> keep flags ----------------
__global__ __launch_bounds__(64) void probs_keep_kernel(const float* __restrict__ x,
        const float* __restrict__ sw, const float* __restrict__ sb,
        unsigned k0, unsigned k1, int* __restrict__ keep){
  int t = blockIdx.x; int lane = threadIdx.x;
  const float* row = x + (size_t)t*512;
  float acc = 0.f;
  #pragma unroll
  for (int i=0;i<8;i++){ int d = lane + (i<<6); acc += row[d]*sw[d]; }
  #pragma unroll
  for (int o=32;o;o>>=1) acc += __shfl_xor(acc, o);
  if (lane==0){
    float z = acc + sb[0];
    float p = 1.f/(1.f + expf(-z));
    unsigned y0,y1; tf2x32(k0,k1, 0u,(unsigned)t, &y0,&y1);
    unsigned bits = y0 ^ y1;
    float u = __uint_as_float((bits>>9) | 0x3f800000u) - 1.0f;
    keep[t] = (u < p) ? 0 : 1;
  }
}

// ---------------- per-row stable compaction map ----------------
__global__ void scan_kernel(const int* __restrict__ keep, int* __restrict__ map,
                            int* __restrict__ nkeep){
  int b = blockIdx.x; int s = threadIdx.x;
  __shared__ int sc[512];
  int k = keep[(b<<9) + s];
  sc[s] = k;
  __syncthreads();
  for (int o=1;o<512;o<<=1){
    int t = (s>=o) ? sc[s-o] : 0;
    __syncthreads();
    sc[s] += t;
    __syncthreads();
  }
  if (k) map[(b<<9) + sc[s] - 1] = s;
  if (s==511) nkeep[b] = sc[511];
}

__global__ void gather_kernel(const float* __restrict__ src, float* __restrict__ dst,
                              const int* __restrict__ map, const int* __restrict__ nkeep){
  int blk = blockIdx.x; int b = blk >> 9; int j = blk & 511; int tid = threadIdx.x;
  float4* drow = (float4*)(dst + (size_t)blk*512);
  if (j < nkeep[b]){
    const float4* srow = (const float4*)(src + (size_t)((b<<9) + map[blk])*512);
    drow[tid] = srow[tid];
  } else {
    drow[tid] = make_float4(0.f,0.f,0.f,0.f);
  }
}

// ---------------- Wq/Wk/Wv [H,D,DK] -> row-major [D, 1536] combined ----------------
__global__ void wqkv_kernel(const float* __restrict__ Wq, const float* __restrict__ Wk,
                            const float* __restrict__ Wv, float* __restrict__ Wt){
  int d = blockIdx.x; int which = blockIdx.y; int c = threadIdx.x;
  const float* src = (which==0)? Wq : (which==1)? Wk : Wv;
  Wt[(size_t)d*1536 + (which<<9) + c] =
      src[(size_t)(c>>6)*32768 + ((size_t)d<<6) + (c&63)];
}

// ---------------- fp32 tiled GEMM 64x64x16 ----------------
template<bool BIAS, bool RES, bool RELU>
__global__ __launch_bounds__(256) void gemm_kernel(const float* __restrict__ A,
        const float* __restrict__ Bm, const float* __restrict__ bias,
        const float* __restrict__ R, float* __restrict__ C, int M, int N, int K){
  __shared__ float As[16][64];
  __shared__ float Bs[16][64];
  int bn = blockIdx.x, bm = blockIdx.y;
  int tid = threadIdx.x;
  int tx = tid & 15, ty = tid >> 4;
  int arow = tid >> 2,  acg = (tid & 3) << 2;
  int brow = tid >> 4,  bcg = (tid & 15) << 2;
  const float* Ab = A + (size_t)bm*64*K;
  const float* Bb = Bm + (bn<<6);
  float acc[4][4] = {};
  for (int k0 = 0; k0 < K; k0 += 16){
    float4 av = *(const float4*)(Ab + (size_t)arow*K + k0 + acg);
    float4 bv = *(const float4*)(Bb + (size_t)(k0+brow)*N + bcg);
    __syncthreads();
    As[acg+0][arow]=av.x; As[acg+1][arow]=av.y; As[acg+2][arow]=av.z; As[acg+3][arow]=av.w;
    *(float4*)&Bs[brow][bcg] = bv;
    __syncthreads();
    #pragma unroll
    for (int kk=0;kk<16;kk++){
      float4 a = *(const float4*)&As[kk][ty<<2];
      float4 b = *(const float4*)&Bs[kk][tx<<2];
      acc[0][0] += a.x*b.x; acc[0][1] += a.x*b.y; acc[0][2] += a.x*b.z; acc[0][3] += a.x*b.w;
      acc[1][0] += a.y*b.x; acc[1][1] += a.y*b.y; acc[1][2] += a.y*b.z; acc[1][3] += a.y*b.w;
      acc[2][0] += a.z*b.x; acc[2][1] += a.z*b.y; acc[2][2] += a.z*b.z; acc[2][3] += a.z*b.w;
      acc[3][0] += a.w*b.x; acc[3][1] += a.w*b.y; acc[3][2] += a.w*b.z; acc[3][3] += a.w*b.w;
    }
  }
  int row0 = (bm<<6) + (ty<<2), col0 = (bn<<6) + (tx<<2);
  #pragma unroll
  for (int i=0;i<4;i++){
    #pragma unroll
    for (int j=0;j<4;j++){
      float v = acc[i][j];
      if (BIAS) v += bias[col0+j];
      if (RES)  v += R[(size_t)(row0+i)*N + col0+j];
      if (RELU) v = fmaxf(v, 0.f);
      C[(size_t)(row0+i)*N + col0+j] = v;
    }
  }
}

// ---------------- flash attention: block = (b, h, 64-query tile), 256 thr ----------------
__global__ __launch_bounds__(256) void fattn_kernel(const float* __restrict__ QKV,
        const float* __restrict__ Xc, float* __restrict__ O){
  __shared__ float QsT[64][68];   // [d][q]
  __shared__ float KsT[64][68];   // [d][k]
  __shared__ float Vs[64][68];    // [k][d]
  __shared__ float PsT[64][68];   // [k][q]
  __shared__ float pads[512];
  int orig = blockIdx.x;
  int wgid = ((orig & 7) << 7) + (orig >> 3);   // XCD-contiguous chunks (1024%8==0)
  int qt = wgid & 7; int bh = wgid >> 3; int h = bh & 7; int b = bh >> 3;
  int tid = threadIdx.x;
  int d4 = tid & 15;          // float4 column index for staging
  int r0 = tid >> 4;          // staging row base 0..15
  size_t rowbase = (size_t)(b << 9) * 1536;
  int q0 = qt << 6;
  const float* Qg = QKV + rowbase + (size_t)q0*1536 + (h<<6);
  #pragma unroll
  for (int rep = 0; rep < 4; rep++){
    int q = r0 + (rep<<4);
    float4 v = *(const float4*)(Qg + (size_t)q*1536 + (d4<<2));
    QsT[(d4<<2)+0][q] = v.x; QsT[(d4<<2)+1][q] = v.y;
    QsT[(d4<<2)+2][q] = v.z; QsT[(d4<<2)+3][q] = v.w;
  }
  pads[tid]     = Xc[(size_t)((b<<9) + tid) << 9];
  pads[tid+256] = Xc[(size_t)((b<<9) + tid + 256) << 9];

  int tx = tid & 15, ty = tid >> 4;   // compute grid: q = ty*4+i, k/d = tx*4+j
  float m[4], l[4], out[4][4];
  #pragma unroll
  for (int i=0;i<4;i++){ m[i] = -3.0e38f; l[i] = 0.f;
    out[i][0]=0.f; out[i][1]=0.f; out[i][2]=0.f; out[i][3]=0.f; }
  const float* Kg = QKV + rowbase + 512 + (h<<6);
  const float* Vg = QKV + rowbase + 1024 + (h<<6);

  for (int kt = 0; kt < 8; kt++){
    __syncthreads();                       // prev PV + prev stage reads done
    #pragma unroll
    for (int rep = 0; rep < 4; rep++){
      int k = r0 + (rep<<4);
      size_t krow = (size_t)((kt<<6) + k)*1536;
      float4 kv = *(const float4*)(Kg + krow + (d4<<2));
      KsT[(d4<<2)+0][k] = kv.x; KsT[(d4<<2)+1][k] = kv.y;
      KsT[(d4<<2)+2][k] = kv.z; KsT[(d4<<2)+3][k] = kv.w;
      float4 vv = *(const float4*)(Vg + krow + (d4<<2));
      *(float4*)&Vs[k][d4<<2] = vv;
    }
    __syncthreads();
    // S-tile: acc[i][j] = sum_d Q[q0+ty*4+i][d] * K[kt*64+tx*4+j][d]
    float acc[4][4] = {};
    #pragma unroll 4
    for (int d = 0; d < 64; d++){
      float4 a  = *(const float4*)&QsT[d][ty<<2];
      float4 bq = *(const float4*)&KsT[d][tx<<2];
      acc[0][0] += a.x*bq.x; acc[0][1] += a.x*bq.y; acc[0][2] += a.x*bq.z; acc[0][3] += a.x*bq.w;
      acc[1][0] += a.y*bq.x; acc[1][1] += a.y*bq.y; acc[1][2] += a.y*bq.z; acc[1][3] += a.y*bq.w;
      acc[2][0] += a.z*bq.x; acc[2][1] += a.z*bq.y; acc[2][2] += a.z*bq.z; acc[2][3] += a.z*bq.w;
      acc[3][0] += a.w*bq.x; acc[3][1] += a.w*bq.y; acc[3][2] += a.w*bq.z; acc[3][3] += a.w*bq.w;
    }
    // scale + pad mask
    int kbase = kt<<6;
    float sv[4][4];
    #pragma unroll
    for (int j=0;j<4;j++){
      bool pad = (pads[kbase + (tx<<2) + j] == 0.f);
      #pragma unroll
      for (int i=0;i<4;i++) sv[i][j] = pad ? NEGV : acc[i][j]*ISCALE;
    }
    // online softmax per q row (reduce over the 16-lane tx group)
    #pragma unroll
    for (int i=0;i<4;i++){
      float tm = fmaxf(fmaxf(sv[i][0],sv[i][1]), fmaxf(sv[i][2],sv[i][3]));
      tm = fmaxf(tm, __shfl_xor(tm,1)); tm = fmaxf(tm, __shfl_xor(tm,2));
      tm = fmaxf(tm, __shfl_xor(tm,4)); tm = fmaxf(tm, __shfl_xor(tm,8));
      float mn = fmaxf(m[i], tm);
      float f  = expf(m[i] - mn);
      m[i] = mn;
      float rs = 0.f;
      #pragma unroll
      for (int j=0;j<4;j++){
        float e = expf(sv[i][j] - mn);
        sv[i][j] = e; rs += e;
      }
      rs += __shfl_xor(rs,1); rs += __shfl_xor(rs,2);
      rs += __shfl_xor(rs,4); rs += __shfl_xor(rs,8);
      l[i] = l[i]*f + rs;
      out[i][0]*=f; out[i][1]*=f; out[i][2]*=f; out[i][3]*=f;
    }
    // P-tile to LDS, transposed: PsT[k][q]
    #pragma unroll
    for (int j=0;j<4;j++){
      float4 pv = make_float4(sv[0][j], sv[1][j], sv[2][j], sv[3][j]);
      *(float4*)&PsT[(tx<<2)+j][ty<<2] = pv;
    }
    __syncthreads();
    // PV: out[i][j] += sum_k P[q][k] * V[k][d]
    #pragma unroll 4
    for (int k=0;k<64;k++){
      float4 a  = *(const float4*)&PsT[k][ty<<2];
      float4 bv = *(const float4*)&Vs[k][tx<<2];
      out[0][0] += a.x*bv.x; out[0][1] += a.x*bv.y; out[0][2] += a.x*bv.z; out[0][3] += a.x*bv.w;
      out[1][0] += a.y*bv.x; out[1][1] += a.y*bv.y; out[1][2] += a.y*bv.z; out[1][3] += a.y*bv.w;
      out[2][0] += a.z*bv.x; out[2][1] += a.z*bv.y; out[2][2] += a.z*bv.z; out[2][3] += a.z*bv.w;
      out[3][0] += a.w*bv.x; out[3][1] += a.w*bv.y; out[3][2] += a.w*bv.z; out[3][3] += a.w*bv.w;
    }
  }
  // epilogue
  size_t obase = ((size_t)(b<<9) + q0) << 9;
  #pragma unroll
  for (int i=0;i<4;i++){
    float inv = 1.f / l[i];
    float4 ov = make_float4(out[i][0]*inv, out[i][1]*inv, out[i][2]*inv, out[i][3]*inv);
    *(float4*)(O + obase + (size_t)((ty<<2)+i)*512 + (h<<6) + (tx<<2)) = ov;
  }
}

// ---------------- LayerNorm ----------------
__global__ __launch_bounds__(256) void ln_kernel(const float* __restrict__ in,
        const float* __restrict__ ga, const float* __restrict__ be, float* __restrict__ out){
  int t = blockIdx.x; int tid = threadIdx.x;
  const float* row = in + (size_t)t*512;
  float v0 = row[tid], v1 = row[tid+256];
  float s = v0 + v1;
  #pragma unroll
  for (int o=32;o;o>>=1) s += __shfl_xor(s,o);
  __shared__ float red[4];
  int wid = tid >> 6, lane = tid & 63;
  if (lane==0) red[wid] = s;
  __syncthreads();
  float mu = (red[0]+red[1]+red[2]+red[3]) * (1.f/512.f);
  float d0 = v0-mu, d1 = v1-mu;
  float q = d0*d0 + d1*d1;
  #pragma unroll
  for (int o=32;o;o>>=1) q += __shfl_xor(q,o);
  __syncthreads();
  if (lane==0) red[wid] = q;
  __syncthreads();
  float var = (red[0]+red[1]+red[2]+red[3]) * (1.f/511.f);
  float inv = 1.f/(sqrtf(var) + 1e-3f);
  float* orow = out + (size_t)t*512;
  orow[tid]     = ga[tid]    *(d0*inv) + be[tid];
  orow[tid+256] = ga[tid+256]*(d1*inv) + be[tid+256];
}

// ---------------- launch ----------------
extern "C" void kernel_launch(void* const* d_in, const int* in_sizes, int n_in,
                              void* d_out, int out_size, void* d_ws, size_t ws_size,
                              hipStream_t stream){
  const int*   seq = (const int*)d_in[0];
  const int*   pos = (const int*)d_in[1];
  const float* we  = (const float*)d_in[2];
  const float* pe  = (const float*)d_in[3];
  const float* Wq  = (const float*)d_in[4];
  const float* Wk  = (const float*)d_in[5];
  const float* Wv  = (const float*)d_in[6];
  const float* Wo  = (const float*)d_in[7];
  const float* bo  = (const float*)d_in[8];
  const float* l1a = (const float*)d_in[9];
  const float* l1b = (const float*)d_in[10];
  const float* w1  = (const float*)d_in[11];
  const float* b1  = (const float*)d_in[12];
  const float* w2  = (const float*)d_in[13];
  const float* b2  = (const float*)d_in[14];
  const float* l2a = (const float*)d_in[15];
  const float* l2b = (const float*)d_in[16];
  const float* sw  = (const float*)d_in[17];
  const float* sb  = (const float*)d_in[18];
  float* out = (float*)d_out;

  const size_t TD = (size_t)8192*512;       // 4M floats
  float* A    = (float*)d_ws;               // x / attn-out / ln-out
  float* Bc   = A  + TD;                    // compacted x (residual)
  float* QKVb = Bc + TD;                    // [8192][1536] fused QKV; reused as P1/Hb
  float* P1   = QKVb;                       // [8192][512] proj / ffn2 out
  float* Hb   = QKVb + TD;                  // [8192][1024] ffn hidden
  float* Wt   = QKVb + 3*TD;                // [512][1536] transposed qkv weights
  int* keep = (int*)(Wt + (size_t)512*1536);
  int* map  = keep + 8192;
  int* nk   = map  + 8192;

  // host-side key chain: rng=key(42); per layer rng,sub = split(rng)
  unsigned r0=0u, r1=42u, subs0[6], subs1[6];
  for (int l=0;l<6;l++){
    unsigned a0,a1,b0,b1;
    tf2x32(r0,r1, 0u,0u, &a0,&a1);
    tf2x32(r0,r1, 0u,1u, &b0,&b1);
    subs0[l]=b0; subs1[l]=b1; r0=a0; r1=a1;
  }

  emb_kernel<<<8192,128,0,stream>>>(seq,pos,we,pe,A);

  for (int l=0;l<6;l++){
    probs_keep_kernel<<<8192,64,0,stream>>>(A, sw + (size_t)l*512, sb + l,
                                            subs0[l], subs1[l], keep);
    scan_kernel<<<16,512,0,stream>>>(keep, map, nk);
    gather_kernel<<<8192,128,0,stream>>>(A, Bc, map, nk);
    wqkv_kernel<<<dim3(512,3),512,0,stream>>>(Wq + (size_t)l*262144,
                                              Wk + (size_t)l*262144,
                                              Wv + (size_t)l*262144, Wt);
    gemm_kernel<false,false,false><<<dim3(24,128),256,0,stream>>>(Bc, Wt,
            nullptr, nullptr, QKVb, 8192,1536,512);
    fattn_kernel<<<1024,256,0,stream>>>(QKVb, Bc, A);
    gemm_kernel<true,true,false><<<dim3(8,128),256,0,stream>>>(A, Wo + (size_t)l*262144,
            bo + (size_t)l*512, Bc, P1, 8192,512,512);
    ln_kernel<<<8192,256,0,stream>>>(P1, l1a + (size_t)l*512, l1b + (size_t)l*512, A);
    gemm_kernel<true,false,true><<<dim3(16,128),256,0,stream>>>(A, w1 + (size_t)l*524288,
            b1 + (size_t)l*1024, nullptr, Hb, 8192,1024,512);
    gemm_kernel<true,true,false><<<dim3(8,128),256,0,stream>>>(Hb, w2 + (size_t)l*524288,
            b2 + (size_t)l*512, A, P1, 8192,512,1024);
    ln_kernel<<<8192,256,0,stream>>>(P1, l2a + (size_t)l*512, l2b + (size_t)l*512,
                                     (l==5)? out : A);
  }
}

// Round 9
// 3141.998 us; speedup vs baseline: 1.6472x; 1.1841x over previous
//
#include <hip/hip_runtime.h>
#include <math.h>

#define NEGV (-1e9f)
#define ISCALE 0.04419417382415922f   // 1/sqrt(512)

typedef __attribute__((ext_vector_type(8))) __bf16 bf16x8;
typedef __attribute__((ext_vector_type(4))) float f32x4;

// ---------------- bf16 helpers (raw-bit, RNE) ----------------
__device__ inline unsigned short f2bf(float x){
  unsigned u = __float_as_uint(x);
  unsigned r = (u + 0x7fffu + ((u>>16)&1u)) >> 16;
  return (unsigned short)r;
}
__device__ inline float bf2f(unsigned short b){ return __uint_as_float((unsigned)b<<16); }

// ---------------- Threefry-2x32 (exact JAX semantics) ----------------
__host__ __device__ inline unsigned rotl32(unsigned v, int d){ return (v<<d)|(v>>(32-d)); }

__host__ __device__ inline void tf2x32(unsigned k0, unsigned k1, unsigned c0, unsigned c1,
                                       unsigned* o0, unsigned* o1){
  unsigned ks2 = k0 ^ k1 ^ 0x1BD11BDAu;
  unsigned x0 = c0 + k0, x1 = c1 + k1;
#define RND(r) { x0 += x1; x1 = rotl32(x1,(r)); x1 ^= x0; }
  RND(13) RND(15) RND(26) RND(6)   x0 += k1;  x1 += ks2 + 1u;
  RND(17) RND(29) RND(16) RND(24)  x0 += ks2; x1 += k0  + 2u;
  RND(13) RND(15) RND(26) RND(6)   x0 += k0;  x1 += k1  + 3u;
  RND(17) RND(29) RND(16) RND(24)  x0 += k1;  x1 += ks2 + 4u;
  RND(13) RND(15) RND(26) RND(6)   x0 += ks2; x1 += k0  + 5u;
#undef RND
  *o0 = x0; *o1 = x1;
}

// ---------------- embedding ----------------
__global__ void emb_kernel(const int* __restrict__ seq, const int* __restrict__ pos,
                           const float* __restrict__ we, const float* __restrict__ pe,
                           float* __restrict__ x){
  int t = blockIdx.x; int tid = threadIdx.x;
  int id = seq[t]; int pp = pos[t];
  float4 w = ((const float4*)(we + (size_t)id*512))[tid];
  float4 p = ((const float4*)(pe + (size_t)pp*512))[tid];
  float4 o; o.x=w.x+p.x; o.y=w.y+p.y; o.z=w.z+p.z; o.w=w.w+p.w;
  ((float4*)(x + (size_t)t*512))[tid] = o;
}

// ---------------- probs -> bernoulli -> keep flags ----------------
__global__ __launch_bounds__(64) void probs_keep_kernel(const float* __restrict__ x,
        const float* __restrict__ sw, const float* __restrict__ sb,
        unsigned k0, unsigned k1, int* __restrict__ keep){
  int t = blockIdx.x; int lane = threadIdx.x;
  const float* row = x + (size_t)t*512;
  float acc = 0.f;
  #pragma unroll
  for (int i=0;i<8;i++){ int d = lane + (i<<6); acc += row[d]*sw[d]; }
  #pragma unroll
  for (int o=32;o;o>>=1) acc += __shfl_xor(acc, o);
  if (lane==0){
    float z = acc + sb[0];
    float p = 1.f/(1.f + expf(-z));
    unsigned y0,y1; tf2x32(k0,k1, 0u,(unsigned)t, &y0,&y1);
    unsigned bits = y0 ^ y1;
    float u = __uint_as_float((bits>>9) | 0x3f800000u) - 1.0f;
    keep[t] = (u < p) ? 0 : 1;
  }
}

// ---------------- per-row stable compaction map ----------------
__global__ void scan_kernel(const int* __restrict__ keep, int* __restrict__ map,
                            int* __restrict__ nkeep){
  int b = blockIdx.x; int s = threadIdx.x;
  __shared__ int sc[512];
  int k = keep[(b<<9) + s];
  sc[s] = k;
  __syncthreads();
  for (int o=1;o<512;o<<=1){
    int t = (s>=o) ? sc[s-o] : 0;
    __syncthreads();
    sc[s] += t;
    __syncthreads();
  }
  if (k) map[(b<<9) + sc[s] - 1] = s;
  if (s==511) nkeep[b] = sc[511];
}

__global__ void gather_kernel(const float* __restrict__ src, float* __restrict__ dst,
                              const int* __restrict__ map, const int* __restrict__ nkeep){
  int blk = blockIdx.x; int b = blk >> 9; int j = blk & 511; int tid = threadIdx.x;
  float4* drow = (float4*)(dst + (size_t)blk*512);
  if (j < nkeep[b]){
    const float4* srow = (const float4*)(src + (size_t)((b<<9) + map[blk])*512);
    drow[tid] = srow[tid];
  } else {
    drow[tid] = make_float4(0.f,0.f,0.f,0.f);
  }
}

// ---------------- Wq/Wk/Wv [H,D,DK] -> row-major [D, 1536] combined ----------------
__global__ void wqkv_kernel(const float* __restrict__ Wq, const float* __restrict__ Wk,
                            const float* __restrict__ Wv, float* __restrict__ Wt){
  int d = blockIdx.x; int which = blockIdx.y; int c = threadIdx.x;
  const float* src = (which==0)? Wq : (which==1)? Wk : Wv;
  Wt[(size_t)d*1536 + (which<<9) + c] =
      src[(size_t)(c>>6)*32768 + ((size_t)d<<6) + (c&63)];
}

// ---------------- activation split: fp32 -> 3 bf16 planes (same layout) ----------------
__global__ __launch_bounds__(256) void split3_kernel(const float* __restrict__ in,
        unsigned short* __restrict__ h, unsigned short* __restrict__ m,
        unsigned short* __restrict__ l, int n){
  int i = (blockIdx.x*256 + threadIdx.x) << 2;
  if (i >= n) return;
  float4 v = *(const float4*)(in + i);
  float xs[4] = {v.x, v.y, v.z, v.w};
  unsigned short ha[4], ma[4], la[4];
  #pragma unroll
  for (int j=0;j<4;j++){
    float x = xs[j];
    unsigned short hh = f2bf(x);
    float r1 = x - bf2f(hh);
    unsigned short mm = f2bf(r1);
    float r2 = r1 - bf2f(mm);
    ha[j]=hh; ma[j]=mm; la[j]=f2bf(r2);
  }
  *(ushort4*)(h+i) = make_ushort4(ha[0],ha[1],ha[2],ha[3]);
  *(ushort4*)(m+i) = make_ushort4(ma[0],ma[1],ma[2],ma[3]);
  *(ushort4*)(l+i) = make_ushort4(la[0],la[1],la[2],la[3]);
}

// ---------------- weight split+transpose: W[K][N] fp32 -> 3 planes [N][K] bf16 --------
__global__ __launch_bounds__(256) void wsplit_kernel(const float* __restrict__ W,
        unsigned short* __restrict__ h, unsigned short* __restrict__ m,
        unsigned short* __restrict__ l, int K, int N){
  __shared__ float T[64][68];
  int k0 = blockIdx.y<<6, n0 = blockIdx.x<<6;
  int tid = threadIdx.x;
  int r = tid >> 4, c4 = tid & 15;
  #pragma unroll
  for (int rep=0; rep<4; rep++){
    int kk = r + (rep<<4);
    float4 v = *(const float4*)(W + (size_t)(k0+kk)*N + n0 + (c4<<2));
    *(float4*)&T[kk][c4<<2] = v;
  }
  __syncthreads();
  #pragma unroll
  for (int rep=0; rep<4; rep++){
    int nn = r + (rep<<4);
    int kk = c4<<2;
    unsigned short ha[4], ma[4], la[4];
    #pragma unroll
    for (int j=0;j<4;j++){
      float x = T[kk+j][nn];
      unsigned short hh = f2bf(x);
      float r1 = x - bf2f(hh);
      unsigned short mm = f2bf(r1);
      float r2 = r1 - bf2f(mm);
      ha[j]=hh; ma[j]=mm; la[j]=f2bf(r2);
    }
    size_t o = (size_t)(n0+nn)*K + k0 + kk;
    *(ushort4*)(h+o) = make_ushort4(ha[0],ha[1],ha[2],ha[3]);
    *(ushort4*)(m+o) = make_ushort4(ma[0],ma[1],ma[2],ma[3]);
    *(ushort4*)(l+o) = make_ushort4(la[0],la[1],la[2],la[3]);
  }
}

// ---------------- split-bf16 MFMA GEMM: C = A@B (+bias)(+R)(relu) ----------------
// A planes [M][K] bf16 bits; B planes [N][K] bf16 bits (pre-transposed).
// 128x128 tile, BK=32, 4 waves of 64x64, mfma_f32_16x16x32_bf16.
template<bool BIAS, bool RES, bool RELU>
__global__ __launch_bounds__(256) void gemm_mfma(
        const unsigned short* __restrict__ Ah, const unsigned short* __restrict__ Am2,
        const unsigned short* __restrict__ Al,
        const unsigned short* __restrict__ Bh, const unsigned short* __restrict__ Bm2,
        const unsigned short* __restrict__ Bl,
        const float* __restrict__ bias, const float* __restrict__ R,
        float* __restrict__ C, int M, int N, int K){
  __shared__ unsigned short As[3][128][40];
  __shared__ unsigned short Bs[3][128][40];
  int bn = blockIdx.x, bm = blockIdx.y;
  int tid = threadIdx.x;
  int w = tid >> 6, lane = tid & 63;
  int wm = w >> 1, wn = w & 1;
  int lrow = lane & 15, kg = lane >> 4;
  const unsigned short* Apl[3] = {Ah, Am2, Al};
  const unsigned short* Bpl[3] = {Bh, Bm2, Bl};

  f32x4 acc[4][4];
  const f32x4 zz = {0.f,0.f,0.f,0.f};
  #pragma unroll
  for (int i=0;i<4;i++)
    #pragma unroll
    for (int j=0;j<4;j++) acc[i][j] = zz;

  int srow = tid >> 1, seg = tid & 1;
  for (int ks = 0; ks < K; ks += 32){
    size_t abase = (size_t)(bm*128 + srow)*K + ks + seg*16;
    size_t bbase = (size_t)(bn*128 + srow)*K + ks + seg*16;
    #pragma unroll
    for (int p=0;p<3;p++){
      const unsigned short* ap = Apl[p] + abase;
      *(uint4*)&As[p][srow][seg*16]   = *(const uint4*)ap;
      *(uint4*)&As[p][srow][seg*16+8] = *(const uint4*)(ap+8);
      const unsigned short* bp = Bpl[p] + bbase;
      *(uint4*)&Bs[p][srow][seg*16]   = *(const uint4*)bp;
      *(uint4*)&Bs[p][srow][seg*16+8] = *(const uint4*)(bp+8);
    }
    __syncthreads();
    bf16x8 bfr[4][3];
    #pragma unroll
    for (int nf=0;nf<4;nf++)
      #pragma unroll
      for (int p=0;p<3;p++)
        bfr[nf][p] = *(const bf16x8*)&Bs[p][(wn<<6)+(nf<<4)+lrow][kg<<3];
    #pragma unroll
    for (int mf=0;mf<4;mf++){
      bf16x8 ah = *(const bf16x8*)&As[0][(wm<<6)+(mf<<4)+lrow][kg<<3];
      bf16x8 am = *(const bf16x8*)&As[1][(wm<<6)+(mf<<4)+lrow][kg<<3];
      bf16x8 al = *(const bf16x8*)&As[2][(wm<<6)+(mf<<4)+lrow][kg<<3];
      #pragma unroll
      for (int nf=0;nf<4;nf++){
        acc[mf][nf] = __builtin_amdgcn_mfma_f32_16x16x32_bf16(ah, bfr[nf][0], acc[mf][nf], 0,0,0);
        acc[mf][nf] = __builtin_amdgcn_mfma_f32_16x16x32_bf16(ah, bfr[nf][1], acc[mf][nf], 0,0,0);
        acc[mf][nf] = __builtin_amdgcn_mfma_f32_16x16x32_bf16(am, bfr[nf][0], acc[mf][nf], 0,0,0);
        acc[mf][nf] = __builtin_amdgcn_mfma_f32_16x16x32_bf16(ah, bfr[nf][2], acc[mf][nf], 0,0,0);
        acc[mf][nf] = __builtin_amdgcn_mfma_f32_16x16x32_bf16(al, bfr[nf][0], acc[mf][nf], 0,0,0);
        acc[mf][nf] = __builtin_amdgcn_mfma_f32_16x16x32_bf16(am, bfr[nf][1], acc[mf][nf], 0,0,0);
      }
    }
    __syncthreads();
  }
  int c0 = (bn<<7) + (wn<<6);
  int r0g = (bm<<7) + (wm<<6);
  #pragma unroll
  for (int mf=0;mf<4;mf++){
    #pragma unroll
    for (int nf=0;nf<4;nf++){
      int col = c0 + (nf<<4) + lrow;
      int rowb = r0g + (mf<<4) + (kg<<2);
      #pragma unroll
      for (int r=0;r<4;r++){
        float v = acc[mf][nf][r];
        if (BIAS) v += bias[col];
        if (RES)  v += R[(size_t)(rowb+r)*N + col];
        if (RELU) v = fmaxf(v, 0.f);
        C[(size_t)(rowb+r)*N + col] = v;
      }
    }
  }
}

// ---------------- fp32 tiled GEMM 64x64x16 (fallback path) ----------------
template<bool BIAS, bool RES, bool RELU>
__global__ __launch_bounds__(256) void gemm_kernel(const float* __restrict__ A,
        const float* __restrict__ Bm, const float* __restrict__ bias,
        const float* __restrict__ R, float* __restrict__ C, int M, int N, int K){
  __shared__ float As[16][64];
  __shared__ float Bs[16][64];
  int bn = blockIdx.x, bm = blockIdx.y;
  int tid = threadIdx.x;
  int tx = tid & 15, ty = tid >> 4;
  int arow = tid >> 2,  acg = (tid & 3) << 2;
  int brow = tid >> 4,  bcg = (tid & 15) << 2;
  const float* Ab = A + (size_t)bm*64*K;
  const float* Bb = Bm + (bn<<6);
  float acc[4][4] = {};
  for (int k0 = 0; k0 < K; k0 += 16){
    float4 av = *(const float4*)(Ab + (size_t)arow*K + k0 + acg);
    float4 bv = *(const float4*)(Bb + (size_t)(k0+brow)*N + bcg);
    __syncthreads();
    As[acg+0][arow]=av.x; As[acg+1][arow]=av.y; As[acg+2][arow]=av.z; As[acg+3][arow]=av.w;
    *(float4*)&Bs[brow][bcg] = bv;
    __syncthreads();
    #pragma unroll
    for (int kk=0;kk<16;kk++){
      float4 a = *(const float4*)&As[kk][ty<<2];
      float4 b = *(const float4*)&Bs[kk][tx<<2];
      acc[0][0] += a.x*b.x; acc[0][1] += a.x*b.y; acc[0][2] += a.x*b.z; acc[0][3] += a.x*b.w;
      acc[1][0] += a.y*b.x; acc[1][1] += a.y*b.y; acc[1][2] += a.y*b.z; acc[1][3] += a.y*b.w;
      acc[2][0] += a.z*b.x; acc[2][1] += a.z*b.y; acc[2][2] += a.z*b.z; acc[2][3] += a.z*b.w;
      acc[3][0] += a.w*b.x; acc[3][1] += a.w*b.y; acc[3][2] += a.w*b.z; acc[3][3] += a.w*b.w;
    }
  }
  int row0 = (bm<<6) + (ty<<2), col0 = (bn<<6) + (tx<<2);
  #pragma unroll
  for (int i=0;i<4;i++){
    #pragma unroll
    for (int j=0;j<4;j++){
      float v = acc[i][j];
      if (BIAS) v += bias[col0+j];
      if (RES)  v += R[(size_t)(row0+i)*N + col0+j];
      if (RELU) v = fmaxf(v, 0.f);
      C[(size_t)(row0+i)*N + col0+j] = v;
    }
  }
}

// ---------------- flash attention: block = (b, h, 64-query tile), 256 thr ----------------
__global__ __launch_bounds__(256) void fattn_kernel(const float* __restrict__ QKV,
        const float* __restrict__ Xc, float* __restrict__ O){
  __shared__ float QsT[64][68];   // [d][q]
  __shared__ float KsT[64][68];   // [d][k]
  __shared__ float Vs[64][68];    // [k][d]
  __shared__ float PsT[64][68];   // [k][q]
  __shared__ float pads[512];
  int orig = blockIdx.x;
  int wgid = ((orig & 7) << 7) + (orig >> 3);   // XCD-contiguous chunks (1024%8==0)
  int qt = wgid & 7; int bh = wgid >> 3; int h = bh & 7; int b = bh >> 3;
  int tid = threadIdx.x;
  int d4 = tid & 15;
  int r0 = tid >> 4;
  size_t rowbase = (size_t)(b << 9) * 1536;
  int q0 = qt << 6;
  const float* Qg = QKV + rowbase + (size_t)q0*1536 + (h<<6);
  #pragma unroll
  for (int rep = 0; rep < 4; rep++){
    int q = r0 + (rep<<4);
    float4 v = *(const float4*)(Qg + (size_t)q*1536 + (d4<<2));
    QsT[(d4<<2)+0][q] = v.x; QsT[(d4<<2)+1][q] = v.y;
    QsT[(d4<<2)+2][q] = v.z; QsT[(d4<<2)+3][q] = v.w;
  }
  pads[tid]     = Xc[(size_t)((b<<9) + tid) << 9];
  pads[tid+256] = Xc[(size_t)((b<<9) + tid + 256) << 9];

  int tx = tid & 15, ty = tid >> 4;
  float m[4], l[4], out[4][4];
  #pragma unroll
  for (int i=0;i<4;i++){ m[i] = -3.0e38f; l[i] = 0.f;
    out[i][0]=0.f; out[i][1]=0.f; out[i][2]=0.f; out[i][3]=0.f; }
  const float* Kg = QKV + rowbase + 512 + (h<<6);
  const float* Vg = QKV + rowbase + 1024 + (h<<6);

  for (int kt = 0; kt < 8; kt++){
    __syncthreads();
    #pragma unroll
    for (int rep = 0; rep < 4; rep++){
      int k = r0 + (rep<<4);
      size_t krow = (size_t)((kt<<6) + k)*1536;
      float4 kv = *(const float4*)(Kg + krow + (d4<<2));
      KsT[(d4<<2)+0][k] = kv.x; KsT[(d4<<2)+1][k] = kv.y;
      KsT[(d4<<2)+2][k] = kv.z; KsT[(d4<<2)+3][k] = kv.w;
      float4 vv = *(const float4*)(Vg + krow + (d4<<2));
      *(float4*)&Vs[k][d4<<2] = vv;
    }
    __syncthreads();
    float acc[4][4] = {};
    #pragma unroll 4
    for (int d = 0; d < 64; d++){
      float4 a  = *(const float4*)&QsT[d][ty<<2];
      float4 bq = *(const float4*)&KsT[d][tx<<2];
      acc[0][0] += a.x*bq.x; acc[0][1] += a.x*bq.y; acc[0][2] += a.x*bq.z; acc[0][3] += a.x*bq.w;
      acc[1][0] += a.y*bq.x; acc[1][1] += a.y*bq.y; acc[1][2] += a.y*bq.z; acc[1][3] += a.y*bq.w;
      acc[2][0] += a.z*bq.x; acc[2][1] += a.z*bq.y; acc[2][2] += a.z*bq.z; acc[2][3] += a.z*bq.w;
      acc[3][0] += a.w*bq.x; acc[3][1] += a.w*bq.y; acc[3][2] += a.w*bq.z; acc[3][3] += a.w*bq.w;
    }
    int kbase = kt<<6;
    float sv[4][4];
    #pragma unroll
    for (int j=0;j<4;j++){
      bool pad = (pads[kbase + (tx<<2) + j] == 0.f);
      #pragma unroll
      for (int i=0;i<4;i++) sv[i][j] = pad ? NEGV : acc[i][j]*ISCALE;
    }
    #pragma unroll
    for (int i=0;i<4;i++){
      float tm = fmaxf(fmaxf(sv[i][0],sv[i][1]), fmaxf(sv[i][2],sv[i][3]));
      tm = fmaxf(tm, __shfl_xor(tm,1)); tm = fmaxf(tm, __shfl_xor(tm,2));
      tm = fmaxf(tm, __shfl_xor(tm,4)); tm = fmaxf(tm, __shfl_xor(tm,8));
      float mn = fmaxf(m[i], tm);
      float f  = expf(m[i] - mn);
      m[i] = mn;
      float rs = 0.f;
      #pragma unroll
      for (int j=0;j<4;j++){
        float e = expf(sv[i][j] - mn);
        sv[i][j] = e; rs += e;
      }
      rs += __shfl_xor(rs,1); rs += __shfl_xor(rs,2);
      rs += __shfl_xor(rs,4); rs += __shfl_xor(rs,8);
      l[i] = l[i]*f + rs;
      out[i][0]*=f; out[i][1]*=f; out[i][2]*=f; out[i][3]*=f;
    }
    #pragma unroll
    for (int j=0;j<4;j++){
      float4 pv = make_float4(sv[0][j], sv[1][j], sv[2][j], sv[3][j]);
      *(float4*)&PsT[(tx<<2)+j][ty<<2] = pv;
    }
    __syncthreads();
    #pragma unroll 4
    for (int k=0;k<64;k++){
      float4 a  = *(const float4*)&PsT[k][ty<<2];
      float4 bv = *(const float4*)&Vs[k][tx<<2];
      out[0][0] += a.x*bv.x; out[0][1] += a.x*bv.y; out[0][2] += a.x*bv.z; out[0][3] += a.x*bv.w;
      out[1][0] += a.y*bv.x; out[1][1] += a.y*bv.y; out[1][2] += a.y*bv.z; out[1][3] += a.y*bv.w;
      out[2][0] += a.z*bv.x; out[2][1] += a.z*bv.y; out[2][2] += a.z*bv.z; out[2][3] += a.z*bv.w;
      out[3][0] += a.w*bv.x; out[3][1] += a.w*bv.y; out[3][2] += a.w*bv.z; out[3][3] += a.w*bv.w;
    }
  }
  size_t obase = ((size_t)(b<<9) + q0) << 9;
  #pragma unroll
  for (int i=0;i<4;i++){
    float inv = 1.f / l[i];
    float4 ov = make_float4(out[i][0]*inv, out[i][1]*inv, out[i][2]*inv, out[i][3]*inv);
    *(float4*)(O + obase + (size_t)((ty<<2)+i)*512 + (h<<6) + (tx<<2)) = ov;
  }
}

// ---------------- LayerNorm ----------------
__global__ __launch_bounds__(256) void ln_kernel(const float* __restrict__ in,
        const float* __restrict__ ga, const float* __restrict__ be, float* __restrict__ out){
  int t = blockIdx.x; int tid = threadIdx.x;
  const float* row = in + (size_t)t*512;
  float v0 = row[tid], v1 = row[tid+256];
  float s = v0 + v1;
  #pragma unroll
  for (int o=32;o;o>>=1) s += __shfl_xor(s,o);
  __shared__ float red[4];
  int wid = tid >> 6, lane = tid & 63;
  if (lane==0) red[wid] = s;
  __syncthreads();
  float mu = (red[0]+red[1]+red[2]+red[3]) * (1.f/512.f);
  float d0 = v0-mu, d1 = v1-mu;
  float q = d0*d0 + d1*d1;
  #pragma unroll
  for (int o=32;o;o>>=1) q += __shfl_xor(q,o);
  __syncthreads();
  if (lane==0) red[wid] = q;
  __syncthreads();
  float var = (red[0]+red[1]+red[2]+red[3]) * (1.f/511.f);
  float inv = 1.f/(sqrtf(var) + 1e-3f);
  float* orow = out + (size_t)t*512;
  orow[tid]     = ga[tid]    *(d0*inv) + be[tid];
  orow[tid+256] = ga[tid+256]*(d1*inv) + be[tid+256];
}

// ---------------- launch ----------------
extern "C" void kernel_launch(void* const* d_in, const int* in_sizes, int n_in,
                              void* d_out, int out_size, void* d_ws, size_t ws_size,
                              hipStream_t stream){
  const int*   seq = (const int*)d_in[0];
  const int*   pos = (const int*)d_in[1];
  const float* we  = (const float*)d_in[2];
  const float* pe  = (const float*)d_in[3];
  const float* Wq  = (const float*)d_in[4];
  const float* Wk  = (const float*)d_in[5];
  const float* Wv  = (const float*)d_in[6];
  const float* Wo  = (const float*)d_in[7];
  const float* bo  = (const float*)d_in[8];
  const float* l1a = (const float*)d_in[9];
  const float* l1b = (const float*)d_in[10];
  const float* w1  = (const float*)d_in[11];
  const float* b1  = (const float*)d_in[12];
  const float* w2  = (const float*)d_in[13];
  const float* b2  = (const float*)d_in[14];
  const float* l2a = (const float*)d_in[15];
  const float* l2b = (const float*)d_in[16];
  const float* sw  = (const float*)d_in[17];
  const float* sb  = (const float*)d_in[18];
  float* out = (float*)d_out;

  const size_t TD = (size_t)8192*512;
  float* A    = (float*)d_ws;
  float* Bc   = A  + TD;
  float* QKVb = Bc + TD;                    // 3*TD
  float* P1   = QKVb;
  float* Hb   = QKVb + TD;
  float* Wt   = QKVb + 3*TD;                // 512*1536
  int* keep = (int*)(Wt + (size_t)512*1536);
  int* map  = keep + 8192;
  int* nk   = map  + 8192;
  // bf16 split planes (MFMA path)
  unsigned short* ap0 = (unsigned short*)(nk + 8192);
  const size_t APS = (size_t)8192*1024;     // max activation plane elems
  unsigned short* ap1 = ap0 + APS;
  unsigned short* ap2 = ap1 + APS;
  unsigned short* wp0 = ap2 + APS;
  const size_t WPS = (size_t)1536*512;      // max weight plane elems
  unsigned short* wp1 = wp0 + WPS;
  unsigned short* wp2 = wp1 + WPS;
  size_t need = (size_t)((char*)(wp2 + WPS) - (char*)d_ws);
  bool mfma_ok = (ws_size >= need);

  unsigned r0=0u, r1=42u, subs0[6], subs1[6];
  for (int l=0;l<6;l++){
    unsigned a0,a1,b0,b1;
    tf2x32(r0,r1, 0u,0u, &a0,&a1);
    tf2x32(r0,r1, 0u,1u, &b0,&b1);
    subs0[l]=b0; subs1[l]=b1; r0=a0; r1=a1;
  }

  emb_kernel<<<8192,128,0,stream>>>(seq,pos,we,pe,A);

  for (int l=0;l<6;l++){
    probs_keep_kernel<<<8192,64,0,stream>>>(A, sw + (size_t)l*512, sb + l,
                                            subs0[l], subs1[l], keep);
    scan_kernel<<<16,512,0,stream>>>(keep, map, nk);
    gather_kernel<<<8192,128,0,stream>>>(A, Bc, map, nk);
    wqkv_kernel<<<dim3(512,3),512,0,stream>>>(Wq + (size_t)l*262144,
                                              Wk + (size_t)l*262144,
                                              Wv + (size_t)l*262144, Wt);
    if (mfma_ok){
      // ---- QKV: [8192x512] @ [512x1536] ----
      split3_kernel<<<4096,256,0,stream>>>(Bc, ap0, ap1, ap2, 8192*512);
      wsplit_kernel<<<dim3(24,8),256,0,stream>>>(Wt, wp0, wp1, wp2, 512, 1536);
      gemm_mfma<false,false,false><<<dim3(12,64),256,0,stream>>>(ap0,ap1,ap2,
              wp0,wp1,wp2, nullptr, nullptr, QKVb, 8192,1536,512);
      fattn_kernel<<<1024,256,0,stream>>>(QKVb, Bc, A);
      // ---- proj: [8192x512] @ [512x512] + bo + residual(Bc) ----
      split3_kernel<<<4096,256,0,stream>>>(A, ap0, ap1, ap2, 8192*512);
      wsplit_kernel<<<dim3(8,8),256,0,stream>>>(Wo + (size_t)l*262144, wp0, wp1, wp2, 512, 512);
      gemm_mfma<true,true,false><<<dim3(4,64),256,0,stream>>>(ap0,ap1,ap2,
              wp0,wp1,wp2, bo + (size_t)l*512, Bc, P1, 8192,512,512);
      ln_kernel<<<8192,256,0,stream>>>(P1, l1a + (size_t)l*512, l1b + (size_t)l*512, A);
      // ---- ffn1: [8192x512] @ [512x1024] + b1, relu ----
      split3_kernel<<<4096,256,0,stream>>>(A, ap0, ap1, ap2, 8192*512);
      wsplit_kernel<<<dim3(16,8),256,0,stream>>>(w1 + (size_t)l*524288, wp0, wp1, wp2, 512, 1024);
      gemm_mfma<true,false,true><<<dim3(8,64),256,0,stream>>>(ap0,ap1,ap2,
              wp0,wp1,wp2, b1 + (size_t)l*1024, nullptr, Hb, 8192,1024,512);
      // ---- ffn2: [8192x1024] @ [1024x512] + b2 + residual(A) ----
      split3_kernel<<<8192,256,0,stream>>>(Hb, ap0, ap1, ap2, 8192*1024);
      wsplit_kernel<<<dim3(8,16),256,0,stream>>>(w2 + (size_t)l*524288, wp0, wp1, wp2, 1024, 512);
      gemm_mfma<true,true,false><<<dim3(4,64),256,0,stream>>>(ap0,ap1,ap2,
              wp0,wp1,wp2, b2 + (size_t)l*512, A, P1, 8192,512,1024);
    } else {
      gemm_kernel<false,false,false><<<dim3(24,128),256,0,stream>>>(Bc, Wt,
              nullptr, nullptr, QKVb, 8192,1536,512);
      fattn_kernel<<<1024,256,0,stream>>>(QKVb, Bc, A);
      gemm_kernel<true,true,false><<<dim3(8,128),256,0,stream>>>(A, Wo + (size_t)l*262144,
              bo + (size_t)l*512, Bc, P1, 8192,512,512);
      ln_kernel<<<8192,256,0,stream>>>(P1, l1a + (size_t)l*512, l1b + (size_t)l*512, A);
      gemm_kernel<true,false,true><<<dim3(16,128),256,0,stream>>>(A, w1 + (size_t)l*524288,
              b1 + (size_t)l*1024, nullptr, Hb, 8192,1024,512);
      gemm_kernel<true,true,false><<<dim3(8,128),256,0,stream>>>(Hb, w2 + (size_t)l*524288,
              b2 + (size_t)l*512, A, P1, 8192,512,1024);
    }
    ln_kernel<<<8192,256,0,stream>>>(P1, l2a + (size_t)l*512, l2b + (size_t)l*512,
                                     (l==5)? out : A);
  }
}

// Round 11
// 2770.900 us; speedup vs baseline: 1.8678x; 1.1339x over previous
//
#include <hip/hip_runtime.h>
#include <math.h>

#define NEGV (-1e9f)
#define ISCALE 0.04419417382415922f   // 1/sqrt(512)

typedef __attribute__((ext_vector_type(8))) _Float16 f16x8;
typedef __attribute__((ext_vector_type(4))) _Float16 f16x4;
typedef __attribute__((ext_vector_type(4))) float f32x4;

// ---------------- fp16 2-plane split: x = h + M/4096, M normal-range ----------------
__device__ inline void split2h(float x, _Float16& H, _Float16& M){
  _Float16 h = (_Float16)x;
  float m = x - (float)h;            // exact (Sterbenz)
  H = h;
  M = (_Float16)(m * 4096.0f);       // |M| <= 2|x| -> normal fp16
}

// ---------------- Threefry-2x32 (exact JAX semantics) ----------------
__host__ __device__ inline unsigned rotl32(unsigned v, int d){ return (v<<d)|(v>>(32-d)); }

__host__ __device__ inline void tf2x32(unsigned k0, unsigned k1, unsigned c0, unsigned c1,
                                       unsigned* o0, unsigned* o1){
  unsigned ks2 = k0 ^ k1 ^ 0x1BD11BDAu;
  unsigned x0 = c0 + k0, x1 = c1 + k1;
#define RND(r) { x0 += x1; x1 = rotl32(x1,(r)); x1 ^= x0; }
  RND(13) RND(15) RND(26) RND(6)   x0 += k1;  x1 += ks2 + 1u;
  RND(17) RND(29) RND(16) RND(24)  x0 += ks2; x1 += k0  + 2u;
  RND(13) RND(15) RND(26) RND(6)   x0 += k0;  x1 += k1  + 3u;
  RND(17) RND(29) RND(16) RND(24)  x0 += k1;  x1 += ks2 + 4u;
  RND(13) RND(15) RND(26) RND(6)   x0 += ks2; x1 += k0  + 5u;
#undef RND
  *o0 = x0; *o1 = x1;
}

// ---------------- embedding ----------------
__global__ void emb_kernel(const int* __restrict__ seq, const int* __restrict__ pos,
                           const float* __restrict__ we, const float* __restrict__ pe,
                           float* __restrict__ x){
  int t = blockIdx.x; int tid = threadIdx.x;
  int id = seq[t]; int pp = pos[t];
  float4 w = ((const float4*)(we + (size_t)id*512))[tid];
  float4 p = ((const float4*)(pe + (size_t)pp*512))[tid];
  float4 o; o.x=w.x+p.x; o.y=w.y+p.y; o.z=w.z+p.z; o.w=w.w+p.w;
  ((float4*)(x + (size_t)t*512))[tid] = o;
}

// ---------------- probs -> bernoulli -> keep flags ----------------
__global__ __launch_bounds__(64) void probs_keep_kernel(const float* __restrict__ x,
        const float* __restrict__ sw, const float* __restrict__ sb,
        unsigned k0, unsigned k1, int* __restrict__ keep){
  int t = blockIdx.x; int lane = threadIdx.x;
  const float* row = x + (size_t)t*512;
  float acc = 0.f;
  #pragma unroll
  for (int i=0;i<8;i++){ int d = lane + (i<<6); acc += row[d]*sw[d]; }
  #pragma unroll
  for (int o=32;o;o>>=1) acc += __shfl_xor(acc, o);
  if (lane==0){
    float z = acc + sb[0];
    float p = 1.f/(1.f + expf(-z));
    unsigned y0,y1; tf2x32(k0,k1, 0u,(unsigned)t, &y0,&y1);
    unsigned bits = y0 ^ y1;
    float u = __uint_as_float((bits>>9) | 0x3f800000u) - 1.0f;
    keep[t] = (u < p) ? 0 : 1;
  }
}

// ---------------- per-row stable compaction map ----------------
__global__ void scan_kernel(const int* __restrict__ keep, int* __restrict__ map,
                            int* __restrict__ nkeep){
  int b = blockIdx.x; int s = threadIdx.x;
  __shared__ int sc[512];
  int k = keep[(b<<9) + s];
  sc[s] = k;
  __syncthreads();
  for (int o=1;o<512;o<<=1){
    int t = (s>=o) ? sc[s-o] : 0;
    __syncthreads();
    sc[s] += t;
    __syncthreads();
  }
  if (k) map[(b<<9) + sc[s] - 1] = s;
  if (s==511) nkeep[b] = sc[511];
}

__global__ void gather_kernel(const float* __restrict__ src, float* __restrict__ dst,
                              const int* __restrict__ map, const int* __restrict__ nkeep){
  int blk = blockIdx.x; int b = blk >> 9; int j = blk & 511; int tid = threadIdx.x;
  float4* drow = (float4*)(dst + (size_t)blk*512);
  if (j < nkeep[b]){
    const float4* srow = (const float4*)(src + (size_t)((b<<9) + map[blk])*512);
    drow[tid] = srow[tid];
  } else {
    drow[tid] = make_float4(0.f,0.f,0.f,0.f);
  }
}

// ---------------- Wq/Wk/Wv [H,D,DK] -> row-major [D, 1536] combined ----------------
__global__ void wqkv_kernel(const float* __restrict__ Wq, const float* __restrict__ Wk,
                            const float* __restrict__ Wv, float* __restrict__ Wt){
  int d = blockIdx.x; int which = blockIdx.y; int c = threadIdx.x;
  const float* src = (which==0)? Wq : (which==1)? Wk : Wv;
  Wt[(size_t)d*1536 + (which<<9) + c] =
      src[(size_t)(c>>6)*32768 + ((size_t)d<<6) + (c&63)];
}

// ---------------- activation split: fp32 -> 2 fp16 planes (same layout) ----------------
__global__ __launch_bounds__(256) void split2_kernel(const float* __restrict__ in,
        _Float16* __restrict__ h, _Float16* __restrict__ m, int n){
  int i = (blockIdx.x*256 + threadIdx.x) << 2;
  if (i >= n) return;
  float4 v = *(const float4*)(in + i);
  float xs[4] = {v.x, v.y, v.z, v.w};
  f16x4 ha, ma;
  #pragma unroll
  for (int j=0;j<4;j++){ _Float16 H,M; split2h(xs[j],H,M); ha[j]=H; ma[j]=M; }
  *(f16x4*)(h+i) = ha;
  *(f16x4*)(m+i) = ma;
}

// ---------------- weight split+transpose: W[K][N] fp32 -> 2 planes [N][K] fp16 --------
__global__ __launch_bounds__(256) void wsplit_kernel(const float* __restrict__ W,
        _Float16* __restrict__ h, _Float16* __restrict__ m, int K, int N){
  __shared__ float T[64][68];
  int k0 = blockIdx.y<<6, n0 = blockIdx.x<<6;
  int tid = threadIdx.x;
  int r = tid >> 4, c4 = tid & 15;
  #pragma unroll
  for (int rep=0; rep<4; rep++){
    int kk = r + (rep<<4);
    float4 v = *(const float4*)(W + (size_t)(k0+kk)*N + n0 + (c4<<2));
    *(float4*)&T[kk][c4<<2] = v;
  }
  __syncthreads();
  #pragma unroll
  for (int rep=0; rep<4; rep++){
    int nn = r + (rep<<4);
    int kk = c4<<2;
    f16x4 ha, ma;
    #pragma unroll
    for (int j=0;j<4;j++){ _Float16 H,M; split2h(T[kk+j][nn],H,M); ha[j]=H; ma[j]=M; }
    size_t o = (size_t)(n0+nn)*K + k0 + kk;
    *(f16x4*)(h+o) = ha;
    *(f16x4*)(m+o) = ma;
  }
}

// ---------------- split-fp16 MFMA GEMM: C = A@B (+bias)(+R)(relu) ----------------
// A planes [M][K] fp16; B planes [N][K] fp16 (pre-transposed).
// C = acc0(hh) + acc1(hM + Mh)/4096.  128x128 tile, BK=32, 4 waves of 64x64.
template<bool BIAS, bool RES, bool RELU>
__global__ __launch_bounds__(256) void gemm_mfma(
        const _Float16* __restrict__ Ah, const _Float16* __restrict__ Am,
        const _Float16* __restrict__ Bh, const _Float16* __restrict__ Bm,
        const float* __restrict__ bias, const float* __restrict__ R,
        float* __restrict__ C, int M, int N, int K){
  __shared__ _Float16 As[2][128][40];
  __shared__ _Float16 Bs[2][128][40];
  int bn = blockIdx.x, bm = blockIdx.y;
  int tid = threadIdx.x;
  int w = tid >> 6, lane = tid & 63;
  int wm = w >> 1, wn = w & 1;
  int lrow = lane & 15, kg = lane >> 4;
  const _Float16* Apl[2] = {Ah, Am};
  const _Float16* Bpl[2] = {Bh, Bm};

  f32x4 acc0[4][4], acc1[4][4];
  const f32x4 zz = {0.f,0.f,0.f,0.f};
  #pragma unroll
  for (int i=0;i<4;i++)
    #pragma unroll
    for (int j=0;j<4;j++){ acc0[i][j] = zz; acc1[i][j] = zz; }

  int srow = tid >> 1, seg = tid & 1;
  for (int ks = 0; ks < K; ks += 32){
    size_t abase = (size_t)(bm*128 + srow)*K + ks + seg*16;
    size_t bbase = (size_t)(bn*128 + srow)*K + ks + seg*16;
    #pragma unroll
    for (int p=0;p<2;p++){
      const _Float16* ap = Apl[p] + abase;
      *(uint4*)&As[p][srow][seg*16]   = *(const uint4*)ap;
      *(uint4*)&As[p][srow][seg*16+8] = *(const uint4*)(ap+8);
      const _Float16* bp = Bpl[p] + bbase;
      *(uint4*)&Bs[p][srow][seg*16]   = *(const uint4*)bp;
      *(uint4*)&Bs[p][srow][seg*16+8] = *(const uint4*)(bp+8);
    }
    __syncthreads();
    f16x8 bfr[4][2];
    #pragma unroll
    for (int nf=0;nf<4;nf++)
      #pragma unroll
      for (int p=0;p<2;p++)
        bfr[nf][p] = *(const f16x8*)&Bs[p][(wn<<6)+(nf<<4)+lrow][kg<<3];
    #pragma unroll
    for (int mf=0;mf<4;mf++){
      f16x8 ah = *(const f16x8*)&As[0][(wm<<6)+(mf<<4)+lrow][kg<<3];
      f16x8 am = *(const f16x8*)&As[1][(wm<<6)+(mf<<4)+lrow][kg<<3];
      #pragma unroll
      for (int nf=0;nf<4;nf++){
        acc0[mf][nf] = __builtin_amdgcn_mfma_f32_16x16x32_f16(ah, bfr[nf][0], acc0[mf][nf], 0,0,0);
        acc1[mf][nf] = __builtin_amdgcn_mfma_f32_16x16x32_f16(ah, bfr[nf][1], acc1[mf][nf], 0,0,0);
        acc1[mf][nf] = __builtin_amdgcn_mfma_f32_16x16x32_f16(am, bfr[nf][0], acc1[mf][nf], 0,0,0);
      }
    }
    __syncthreads();
  }
  int c0 = (bn<<7) + (wn<<6);
  int r0g = (bm<<7) + (wm<<6);
  #pragma unroll
  for (int mf=0;mf<4;mf++){
    #pragma unroll
    for (int nf=0;nf<4;nf++){
      int col = c0 + (nf<<4) + lrow;
      int rowb = r0g + (mf<<4) + (kg<<2);
      #pragma unroll
      for (int r=0;r<4;r++){
        float v = acc0[mf][nf][r] + acc1[mf][nf][r] * (1.0f/4096.0f);
        if (BIAS) v += bias[col];
        if (RES)  v += R[(size_t)(rowb+r)*N + col];
        if (RELU) v = fmaxf(v, 0.f);
        C[(size_t)(rowb+r)*N + col] = v;
      }
    }
  }
}

// ---------------- fp32 tiled GEMM 64x64x16 (fallback path) ----------------
template<bool BIAS, bool RES, bool RELU>
__global__ __launch_bounds__(256) void gemm_kernel(const float* __restrict__ A,
        const float* __restrict__ Bm, const float* __restrict__ bias,
        const float* __restrict__ R, float* __restrict__ C, int M, int N, int K){
  __shared__ float As[16][64];
  __shared__ float Bs[16][64];
  int bn = blockIdx.x, bm = blockIdx.y;
  int tid = threadIdx.x;
  int tx = tid & 15, ty = tid >> 4;
  int arow = tid >> 2,  acg = (tid & 3) << 2;
  int brow = tid >> 4,  bcg = (tid & 15) << 2;
  const float* Ab = A + (size_t)bm*64*K;
  const float* Bb = Bm + (bn<<6);
  float acc[4][4] = {};
  for (int k0 = 0; k0 < K; k0 += 16){
    float4 av = *(const float4*)(Ab + (size_t)arow*K + k0 + acg);
    float4 bv = *(const float4*)(Bb + (size_t)(k0+brow)*N + bcg);
    __syncthreads();
    As[acg+0][arow]=av.x; As[acg+1][arow]=av.y; As[acg+2][arow]=av.z; As[acg+3][arow]=av.w;
    *(float4*)&Bs[brow][bcg] = bv;
    __syncthreads();
    #pragma unroll
    for (int kk=0;kk<16;kk++){
      float4 a = *(const float4*)&As[kk][ty<<2];
      float4 b = *(const float4*)&Bs[kk][tx<<2];
      acc[0][0] += a.x*b.x; acc[0][1] += a.x*b.y; acc[0][2] += a.x*b.z; acc[0][3] += a.x*b.w;
      acc[1][0] += a.y*b.x; acc[1][1] += a.y*b.y; acc[1][2] += a.y*b.z; acc[1][3] += a.y*b.w;
      acc[2][0] += a.z*b.x; acc[2][1] += a.z*b.y; acc[2][2] += a.z*b.z; acc[2][3] += a.z*b.w;
      acc[3][0] += a.w*b.x; acc[3][1] += a.w*b.y; acc[3][2] += a.w*b.z; acc[3][3] += a.w*b.w;
    }
  }
  int row0 = (bm<<6) + (ty<<2), col0 = (bn<<6) + (tx<<2);
  #pragma unroll
  for (int i=0;i<4;i++){
    #pragma unroll
    for (int j=0;j<4;j++){
      float v = acc[i][j];
      if (BIAS) v += bias[col0+j];
      if (RES)  v += R[(size_t)(row0+i)*N + col0+j];
      if (RELU) v = fmaxf(v, 0.f);
      C[(size_t)(row0+i)*N + col0+j] = v;
    }
  }
}

// ---------------- flash attention: block = (b, h, 64-query tile), 256 thr ----------------
__global__ __launch_bounds__(256) void fattn_kernel(const float* __restrict__ QKV,
        const float* __restrict__ Xc, float* __restrict__ O){
  __shared__ float QsT[64][68];   // [d][q]
  __shared__ float KsT[64][68];   // [d][k]
  __shared__ float Vs[64][68];    // [k][d]
  __shared__ float PsT[64][68];   // [k][q]
  __shared__ float pads[512];
  int orig = blockIdx.x;
  int wgid = ((orig & 7) << 7) + (orig >> 3);   // XCD-contiguous chunks (1024%8==0)
  int qt = wgid & 7; int bh = wgid >> 3; int h = bh & 7; int b = bh >> 3;
  int tid = threadIdx.x;
  int d4 = tid & 15;
  int r0 = tid >> 4;
  size_t rowbase = (size_t)(b << 9) * 1536;
  int q0 = qt << 6;
  const float* Qg = QKV + rowbase + (size_t)q0*1536 + (h<<6);
  #pragma unroll
  for (int rep = 0; rep < 4; rep++){
    int q = r0 + (rep<<4);
    float4 v = *(const float4*)(Qg + (size_t)q*1536 + (d4<<2));
    QsT[(d4<<2)+0][q] = v.x; QsT[(d4<<2)+1][q] = v.y;
    QsT[(d4<<2)+2][q] = v.z; QsT[(d4<<2)+3][q] = v.w;
  }
  pads[tid]     = Xc[(size_t)((b<<9) + tid) << 9];
  pads[tid+256] = Xc[(size_t)((b<<9) + tid + 256) << 9];

  int tx = tid & 15, ty = tid >> 4;
  float m[4], l[4], out[4][4];
  #pragma unroll
  for (int i=0;i<4;i++){ m[i] = -3.0e38f; l[i] = 0.f;
    out[i][0]=0.f; out[i][1]=0.f; out[i][2]=0.f; out[i][3]=0.f; }
  const float* Kg = QKV + rowbase + 512 + (h<<6);
  const float* Vg = QKV + rowbase + 1024 + (h<<6);

  for (int kt = 0; kt < 8; kt++){
    __syncthreads();
    #pragma unroll
    for (int rep = 0; rep < 4; rep++){
      int k = r0 + (rep<<4);
      size_t krow = (size_t)((kt<<6) + k)*1536;
      float4 kv = *(const float4*)(Kg + krow + (d4<<2));
      KsT[(d4<<2)+0][k] = kv.x; KsT[(d4<<2)+1][k] = kv.y;
      KsT[(d4<<2)+2][k] = kv.z; KsT[(d4<<2)+3][k] = kv.w;
      float4 vv = *(const float4*)(Vg + krow + (d4<<2));
      *(float4*)&Vs[k][d4<<2] = vv;
    }
    __syncthreads();
    float acc[4][4] = {};
    #pragma unroll 4
    for (int d = 0; d < 64; d++){
      float4 a  = *(const float4*)&QsT[d][ty<<2];
      float4 bq = *(const float4*)&KsT[d][tx<<2];
      acc[0][0] += a.x*bq.x; acc[0][1] += a.x*bq.y; acc[0][2] += a.x*bq.z; acc[0][3] += a.x*bq.w;
      acc[1][0] += a.y*bq.x; acc[1][1] += a.y*bq.y; acc[1][2] += a.y*bq.z; acc[1][3] += a.y*bq.w;
      acc[2][0] += a.z*bq.x; acc[2][1] += a.z*bq.y; acc[2][2] += a.z*bq.z; acc[2][3] += a.z*bq.w;
      acc[3][0] += a.w*bq.x; acc[3][1] += a.w*bq.y; acc[3][2] += a.w*bq.z; acc[3][3] += a.w*bq.w;
    }
    int kbase = kt<<6;
    float sv[4][4];
    #pragma unroll
    for (int j=0;j<4;j++){
      bool pad = (pads[kbase + (tx<<2) + j] == 0.f);
      #pragma unroll
      for (int i=0;i<4;i++) sv[i][j] = pad ? NEGV : acc[i][j]*ISCALE;
    }
    #pragma unroll
    for (int i=0;i<4;i++){
      float tm = fmaxf(fmaxf(sv[i][0],sv[i][1]), fmaxf(sv[i][2],sv[i][3]));
      tm = fmaxf(tm, __shfl_xor(tm,1)); tm = fmaxf(tm, __shfl_xor(tm,2));
      tm = fmaxf(tm, __shfl_xor(tm,4)); tm = fmaxf(tm, __shfl_xor(tm,8));
      float mn = fmaxf(m[i], tm);
      float f  = expf(m[i] - mn);
      m[i] = mn;
      float rs = 0.f;
      #pragma unroll
      for (int j=0;j<4;j++){
        float e = expf(sv[i][j] - mn);
        sv[i][j] = e; rs += e;
      }
      rs += __shfl_xor(rs,1); rs += __shfl_xor(rs,2);
      rs += __shfl_xor(rs,4); rs += __shfl_xor(rs,8);
      l[i] = l[i]*f + rs;
      out[i][0]*=f; out[i][1]*=f; out[i][2]*=f; out[i][3]*=f;
    }
    #pragma unroll
    for (int j=0;j<4;j++){
      float4 pv = make_float4(sv[0][j], sv[1][j], sv[2][j], sv[3][j]);
      *(float4*)&PsT[(tx<<2)+j][ty<<2] = pv;
    }
    __syncthreads();
    #pragma unroll 4
    for (int k=0;k<64;k++){
      float4 a  = *(const float4*)&PsT[k][ty<<2];
      float4 bv = *(const float4*)&Vs[k][tx<<2];
      out[0][0] += a.x*bv.x; out[0][1] += a.x*bv.y; out[0][2] += a.x*bv.z; out[0][3] += a.x*bv.w;
      out[1][0] += a.y*bv.x; out[1][1] += a.y*bv.y; out[1][2] += a.y*bv.z; out[1][3] += a.y*bv.w;
      out[2][0] += a.z*bv.x; out[2][1] += a.z*bv.y; out[2][2] += a.z*bv.z; out[2][3] += a.z*bv.w;
      out[3][0] += a.w*bv.x; out[3][1] += a.w*bv.y; out[3][2] += a.w*bv.z; out[3][3] += a.w*bv.w;
    }
  }
  size_t obase = ((size_t)(b<<9) + q0) << 9;
  #pragma unroll
  for (int i=0;i<4;i++){
    float inv = 1.f / l[i];
    float4 ov = make_float4(out[i][0]*inv, out[i][1]*inv, out[i][2]*inv, out[i][3]*inv);
    *(float4*)(O + obase + (size_t)((ty<<2)+i)*512 + (h<<6) + (tx<<2)) = ov;
  }
}

// ---------------- LayerNorm ----------------
__global__ __launch_bounds__(256) void ln_kernel(const float* __restrict__ in,
        const float* __restrict__ ga, const float* __restrict__ be, float* __restrict__ out){
  int t = blockIdx.x; int tid = threadIdx.x;
  const float* row = in + (size_t)t*512;
  float v0 = row[tid], v1 = row[tid+256];
  float s = v0 + v1;
  #pragma unroll
  for (int o=32;o;o>>=1) s += __shfl_xor(s,o);
  __shared__ float red[4];
  int wid = tid >> 6, lane = tid & 63;
  if (lane==0) red[wid] = s;
  __syncthreads();
  float mu = (red[0]+red[1]+red[2]+red[3]) * (1.f/512.f);
  float d0 = v0-mu, d1 = v1-mu;
  float q = d0*d0 + d1*d1;
  #pragma unroll
  for (int o=32;o;o>>=1) q += __shfl_xor(q,o);
  __syncthreads();
  if (lane==0) red[wid] = q;
  __syncthreads();
  float var = (red[0]+red[1]+red[2]+red[3]) * (1.f/511.f);
  float inv = 1.f/(sqrtf(var) + 1e-3f);
  float* orow = out + (size_t)t*512;
  orow[tid]     = ga[tid]    *(d0*inv) + be[tid];
  orow[tid+256] = ga[tid+256]*(d1*inv) + be[tid+256];
}

// ---------------- launch ----------------
extern "C" void kernel_launch(void* const* d_in, const int* in_sizes, int n_in,
                              void* d_out, int out_size, void* d_ws, size_t ws_size,
                              hipStream_t stream){
  const int*   seq = (const int*)d_in[0];
  const int*   pos = (const int*)d_in[1];
  const float* we  = (const float*)d_in[2];
  const float* pe  = (const float*)d_in[3];
  const float* Wq  = (const float*)d_in[4];
  const float* Wk  = (const float*)d_in[5];
  const float* Wv  = (const float*)d_in[6];
  const float* Wo  = (const float*)d_in[7];
  const float* bo  = (const float*)d_in[8];
  const float* l1a = (const float*)d_in[9];
  const float* l1b = (const float*)d_in[10];
  const float* w1  = (const float*)d_in[11];
  const float* b1  = (const float*)d_in[12];
  const float* w2  = (const float*)d_in[13];
  const float* b2  = (const float*)d_in[14];
  const float* l2a = (const float*)d_in[15];
  const float* l2b = (const float*)d_in[16];
  const float* sw  = (const float*)d_in[17];
  const float* sb  = (const float*)d_in[18];
  float* out = (float*)d_out;

  const size_t TD = (size_t)8192*512;
  float* A    = (float*)d_ws;
  float* Bc   = A  + TD;
  float* QKVb = Bc + TD;                    // 3*TD
  float* P1   = QKVb;
  float* Hb   = QKVb + TD;
  float* Wt   = QKVb + 3*TD;                // 512*1536
  int* keep = (int*)(Wt + (size_t)512*1536);
  int* map  = keep + 8192;
  int* nk   = map  + 8192;
  // fp16 split planes (MFMA path)
  _Float16* ap0 = (_Float16*)(nk + 8192);
  const size_t APS = (size_t)8192*1024;     // max activation plane elems
  _Float16* ap1 = ap0 + APS;
  _Float16* wp0 = ap1 + APS;
  const size_t WPS = (size_t)1536*512;      // max weight plane elems
  _Float16* wp1 = wp0 + WPS;
  size_t need = (size_t)((char*)(wp1 + WPS) - (char*)d_ws);
  bool mfma_ok = (ws_size >= need);

  unsigned r0=0u, r1=42u, subs0[6], subs1[6];
  for (int l=0;l<6;l++){
    unsigned a0,a1,b0,b1;
    tf2x32(r0,r1, 0u,0u, &a0,&a1);
    tf2x32(r0,r1, 0u,1u, &b0,&b1);
    subs0[l]=b0; subs1[l]=b1; r0=a0; r1=a1;
  }

  emb_kernel<<<8192,128,0,stream>>>(seq,pos,we,pe,A);

  for (int l=0;l<6;l++){
    probs_keep_kernel<<<8192,64,0,stream>>>(A, sw + (size_t)l*512, sb + l,
                                            subs0[l], subs1[l], keep);
    scan_kernel<<<16,512,0,stream>>>(keep, map, nk);
    gather_kernel<<<8192,128,0,stream>>>(A, Bc, map, nk);
    wqkv_kernel<<<dim3(512,3),512,0,stream>>>(Wq + (size_t)l*262144,
                                              Wk + (size_t)l*262144,
                                              Wv + (size_t)l*262144, Wt);
    if (mfma_ok){
      // ---- QKV: [8192x512] @ [512x1536] ----
      split2_kernel<<<4096,256,0,stream>>>(Bc, ap0, ap1, 8192*512);
      wsplit_kernel<<<dim3(24,8),256,0,stream>>>(Wt, wp0, wp1, 512, 1536);
      gemm_mfma<false,false,false><<<dim3(12,64),256,0,stream>>>(ap0,ap1,
              wp0,wp1, nullptr, nullptr, QKVb, 8192,1536,512);
      fattn_kernel<<<1024,256,0,stream>>>(QKVb, Bc, A);
      // ---- proj: [8192x512] @ [512x512] + bo + residual(Bc) ----
      split2_kernel<<<4096,256,0,stream>>>(A, ap0, ap1, 8192*512);
      wsplit_kernel<<<dim3(8,8),256,0,stream>>>(Wo + (size_t)l*262144, wp0, wp1, 512, 512);
      gemm_mfma<true,true,false><<<dim3(4,64),256,0,stream>>>(ap0,ap1,
              wp0,wp1, bo + (size_t)l*512, Bc, P1, 8192,512,512);
      ln_kernel<<<8192,256,0,stream>>>(P1, l1a + (size_t)l*512, l1b + (size_t)l*512, A);
      // ---- ffn1: [8192x512] @ [512x1024] + b1, relu ----
      split2_kernel<<<4096,256,0,stream>>>(A, ap0, ap1, 8192*512);
      wsplit_kernel<<<dim3(16,8),256,0,stream>>>(w1 + (size_t)l*524288, wp0, wp1, 512, 1024);
      gemm_mfma<true,false,true><<<dim3(8,64),256,0,stream>>>(ap0,ap1,
              wp0,wp1, b1 + (size_t)l*1024, nullptr, Hb, 8192,1024,512);
      // ---- ffn2: [8192x1024] @ [1024x512] + b2 + residual(A) ----
      split2_kernel<<<8192,256,0,stream>>>(Hb, ap0, ap1, 8192*1024);
      wsplit_kernel<<<dim3(8,16),256,0,stream>>>(w2 + (size_t)l*524288, wp0, wp1, 1024, 512);
      gemm_mfma<true,true,false><<<dim3(4,64),256,0,stream>>>(ap0,ap1,
              wp0,wp1, b2 + (size_t)l*512, A, P1, 8192,512,1024);
    } else {
      gemm_kernel<false,false,false><<<dim3(24,128),256,0,stream>>>(Bc, Wt,
              nullptr, nullptr, QKVb, 8192,1536,512);
      fattn_kernel<<<1024,256,0,stream>>>(QKVb, Bc, A);
      gemm_kernel<true,true,false><<<dim3(8,128),256,0,stream>>>(A, Wo + (size_t)l*262144,
              bo + (size_t)l*512, Bc, P1, 8192,512,512);
      ln_kernel<<<8192,256,0,stream>>>(P1, l1a + (size_t)l*512, l1b + (size_t)l*512, A);
      gemm_kernel<true,false,true><<<dim3(16,128),256,0,stream>>>(A, w1 + (size_t)l*524288,
              b1 + (size_t)l*1024, nullptr, Hb, 8192,1024,512);
      gemm_kernel<true,true,false><<<dim3(8,128),256,0,stream>>>(Hb, w2 + (size_t)l*524288,
              b2 + (size_t)l*512, A, P1, 8192,512,1024);
    }
    ln_kernel<<<8192,256,0,stream>>>(P1, l2a + (size_t)l*512, l2b + (size_t)l*512,
                                     (l==5)? out : A);
  }
}